// Round 8
// baseline (1456.518 us; speedup 1.0000x reference)
//
#include <hip/hip_runtime.h>

#define NN 100000
#define NE 3200000
#define F 64
#define NR 8
#define PAD 68                 // LDS row stride (floats); all access worst 2-way (free)
#define NCB 98                 // coarse buckets = ceil(NN/1024), bucket = dst>>10
#define CAPC 36864             // capacity per coarse bucket (mean 32768, +22 sigma)
#define CHUNKA 4000            // edges per binA block (800 blocks)
#define NT 1563                // node tiles = ceil(NN/64)
#define SLCAP 2560             // per-tile edge list capacity (mean 2048, +11 sigma)

// ---------------- init: per-coarse-bucket staging cursors -------------------
__global__ __launch_bounds__(128) void init_kernel(int* __restrict__ cursors) {
    int t = threadIdx.x;
    if (t < NCB) cursors[t] = t * CAPC;
}

// ---------------- pass A: coarse-bin edges (4-copy LDS multi-split) ---------
__global__ __launch_bounds__(256) void binA_kernel(
    const int* __restrict__ esrc, const int* __restrict__ edst,
    const int* __restrict__ etyp,
    int* __restrict__ cursors, uint2* __restrict__ stag8)
{
    __shared__ int hist[128][4];
    __shared__ int start[128];
    __shared__ int cur[128][4];
    __shared__ int gbase[NCB];
    __shared__ uint2 recs[CHUNKA];   // 32 KB

    const int t = threadIdx.x;
    const int cp = t & 3;
    const int e0 = blockIdx.x * CHUNKA;

    if (t < 128) ((int4*)hist)[t] = make_int4(0, 0, 0, 0);
    __syncthreads();

    uint2 rec[16];
#pragma unroll
    for (int j = 0; j < 16; j++) {
        int i = t + j * 256;
        if (i < CHUNKA) {
            int e = e0 + i;
            unsigned s = (unsigned)esrc[e];
            unsigned d = (unsigned)edst[e];
            unsigned r = (unsigned)etyp[e];
            rec[j] = make_uint2(s, d | (r << 17));
            atomicAdd(&hist[d >> 10][cp], 1);
        }
    }
    __syncthreads();

    int tot = 0;
    if (t < 128) {
        int4 h4 = ((int4*)hist)[t];
        tot = h4.x + h4.y + h4.z + h4.w;
        start[t] = tot;
    }
    __syncthreads();
    for (int off = 1; off < 128; off <<= 1) {
        int v = 0;
        if (t < 128 && t >= off) v = start[t - off];
        __syncthreads();
        if (t < 128) start[t] += v;
        __syncthreads();
    }
    if (t < 128) start[t] -= tot;   // inclusive -> exclusive
    __syncthreads();
    if (t < NCB) {
        int4 h4 = ((int4*)hist)[t];
        int s = start[t];
        cur[t][0] = s;
        cur[t][1] = s + h4.x;
        cur[t][2] = s + h4.x + h4.y;
        cur[t][3] = s + h4.x + h4.y + h4.z;
        gbase[t] = atomicAdd(&cursors[t], tot);   // reserve global run
    }
    __syncthreads();

#pragma unroll
    for (int j = 0; j < 16; j++) {
        int i = t + j * 256;
        if (i < CHUNKA) {
            int b = (int)((rec[j].y & 0x1FFFFu) >> 10);
            int slot = atomicAdd(&cur[b][cp], 1);
            recs[slot] = rec[j];
        }
    }
    __syncthreads();

    // burst write-out: consecutive slots -> consecutive global addrs (~41/run)
#pragma unroll
    for (int j = 0; j < 16; j++) {
        int i = t + j * 256;
        if (i < CHUNKA) {
            uint2 rr = recs[i];
            int b = (int)((rr.y & 0x1FFFFu) >> 10);
            stag8[gbase[b] + (i - start[b])] = rr;
        }
    }
}

// ---------------- pass B: fine-bin, 8 chunk-blocks per coarse bucket --------
__global__ __launch_bounds__(256) void binB_kernel(
    const uint2* __restrict__ stag8, const int* __restrict__ cursors,
    unsigned* __restrict__ packed4, unsigned* __restrict__ runsd)
{
    __shared__ int h[16][4];
    __shared__ int cu[16][4];
    const int b = blockIdx.x >> 3;
    const int c = blockIdx.x & 7;
    const int t = threadIdx.x;
    const int cp = t & 3;
    const int bbase = b * CAPC;
    const int n = cursors[b] - bbase;
    const int s = (int)(((long long)c * n) >> 3);
    const int e = (int)(((long long)(c + 1) * n) >> 3);
    const int base = bbase + s;
    const int cn = e - s;

    if (t < 64) ((int*)h)[t] = 0;
    __syncthreads();
    for (int i = t; i < cn; i += 256) {
        unsigned y = stag8[base + i].y;
        atomicAdd(&h[(y >> 6) & 15][cp], 1);
    }
    __syncthreads();
    if (t == 0) {
        int acc = 0;
        for (int f = 0; f < 16; f++) {
            int fstart = acc;
#pragma unroll
            for (int k = 0; k < 4; k++) { cu[f][k] = acc; acc += h[f][k]; }
            runsd[(blockIdx.x << 4) + f] = ((unsigned)(base + fstart) << 10) | (unsigned)(acc - fstart);
        }
    }
    __syncthreads();
    for (int i = t; i < cn; i += 256) {
        uint2 rr = stag8[base + i];
        unsigned f = (rr.y >> 6) & 15u;
        int p = atomicAdd(&cu[f][cp], 1);
        unsigned d = rr.y & 0x1FFFFu;
        unsigned r = rr.y >> 17;
        packed4[base + p] = rr.x | ((d & 63u) << 17) | (r << 23);
    }
}

// ---------------- fused: sort + edge-parallel ds_add gather + GEMM ----------
__global__ __launch_bounds__(256) void fused_kernel(
    const float* __restrict__ x,
    const unsigned* __restrict__ packed4,
    const unsigned* __restrict__ runsd,
    const float* __restrict__ weight,
    const float* __restrict__ root,
    const float* __restrict__ bias,
    float* __restrict__ out)
{
    __shared__ float As[64][PAD];       // As[node][k]
    __shared__ float Bs[64][PAD];       // Bs[k][fout]
    __shared__ int kstart[512];
    __shared__ int kcur[512];
    __shared__ float invk[512];
    __shared__ int slist[SLCAP];        // src | dstLow<<17
    __shared__ unsigned rdesc[8];

    const int t = threadIdx.x;
    const int tile = blockIdx.x;

    if (t < 8) rdesc[t] = runsd[(((tile >> 4) * 8 + t) << 4) + (tile & 15)];
    kstart[t] = 0; kstart[t + 256] = 0;
    __syncthreads();

    // ---- hist by key9 = rel*64 + dstLow ----
#pragma unroll
    for (int c = 0; c < 8; c++) {
        unsigned d = rdesc[c];
        int rs = (int)(d >> 10), rc = (int)(d & 1023u);
        for (int i = t; i < rc; i += 256)
            atomicAdd(&kstart[packed4[rs + i] >> 17], 1);
    }
    __syncthreads();
    int a0 = kstart[2 * t], a1 = kstart[2 * t + 1];
    int psum = a0 + a1;
    kcur[t] = psum;
    __syncthreads();
    for (int off = 1; off < 256; off <<= 1) {
        int v = (t >= off) ? kcur[t - off] : 0;
        __syncthreads();
        kcur[t] += v;
        __syncthreads();
    }
    int ebase = kcur[t] - psum;
    __syncthreads();
    kstart[2 * t]     = ebase;
    kstart[2 * t + 1] = ebase + a0;
    kcur[2 * t]       = ebase;
    kcur[2 * t + 1]   = ebase + a0;
    __syncthreads();
#pragma unroll
    for (int c = 0; c < 8; c++) {
        unsigned d = rdesc[c];
        int rs = (int)(d >> 10), rc = (int)(d & 1023u);
        for (int i = t; i < rc; i += 256) {
            unsigned p = packed4[rs + i];
            int slot = atomicAdd(&kcur[p >> 17], 1);
            slist[slot] = (int)(p & 0x7FFFFFu);   // src + dstLow
        }
    }
    __syncthreads();   // kcur[k] == end of run k

    // per-key inverse counts (2 keys per thread)
    invk[2 * t]     = 1.0f / (float)max(kcur[2 * t]     - kstart[2 * t],     1);
    invk[2 * t + 1] = 1.0f / (float)max(kcur[2 * t + 1] - kstart[2 * t + 1], 1);

    const int lane = t & 63;
    const int w = t >> 6;
    const int node0 = tile * 64;
    const int tx = t & 15;
    const int ty = t >> 4;

    float4 acc[4];
#pragma unroll
    for (int i = 0; i < 4; i++) acc[i] = make_float4(0.f, 0.f, 0.f, 0.f);

    for (int seg = 0; seg < 9; seg++) {
        const float* __restrict__ Wseg = (seg == 0) ? root : (weight + (size_t)(seg - 1) * (F * F));
        __syncthreads();   // As/Bs free (prev GEMM done); invk ready (1st iter)
        // stage B
#pragma unroll
        for (int j = 0; j < 4; j++) {
            int g = j * 1024 + t * 4;
            float4 v = *(const float4*)(Wseg + g);
            *(float4*)&Bs[g >> 6][g & 63] = v;
        }
        if (seg > 0) {
            for (int i = t; i < 64 * PAD; i += 256) ((float*)As)[i] = 0.f;
        }
        __syncthreads();

        if (seg == 0) {
            for (int nn = w * 16; nn < w * 16 + 16; nn++) {
                int node = min(node0 + nn, NN - 1);
                As[nn][lane] = x[(size_t)node * F + lane];
            }
        } else {
            const int kb = (seg - 1) << 6;
            const int beg = kstart[kb];
            const int end = kcur[kb | 63];
            // edge-parallel: whole wave = one edge; 8 independent edges in flight
            for (int i = beg + w * 8; i < end; i += 32) {
                if (i + 8 <= end) {
                    int vv[8]; float ff[8], ss[8];
#pragma unroll
                    for (int j = 0; j < 8; j++) vv[j] = slist[i + j];
#pragma unroll
                    for (int j = 0; j < 8; j++)
                        ff[j] = x[(size_t)(vv[j] & 0x1FFFF) * F + lane];
#pragma unroll
                    for (int j = 0; j < 8; j++) ss[j] = invk[kb + (vv[j] >> 17)];
#pragma unroll
                    for (int j = 0; j < 8; j++)
                        atomicAdd(&As[vv[j] >> 17][lane], ff[j] * ss[j]);
                } else {
                    for (int jj = i; jj < end; jj++) {
                        int v = slist[jj];
                        float f = x[(size_t)(v & 0x1FFFF) * F + lane];
                        atomicAdd(&As[v >> 17][lane], f * invk[kb + (v >> 17)]);
                    }
                }
            }
        }
        __syncthreads();

        // GEMM: 4x4 register tile, k-blocked by 4, all-b128 LDS reads
#pragma unroll 4
        for (int k4 = 0; k4 < 64; k4 += 4) {
            float4 b0 = *(const float4*)&Bs[k4 + 0][tx << 2];
            float4 b1 = *(const float4*)&Bs[k4 + 1][tx << 2];
            float4 b2 = *(const float4*)&Bs[k4 + 2][tx << 2];
            float4 b3 = *(const float4*)&Bs[k4 + 3][tx << 2];
#pragma unroll
            for (int i = 0; i < 4; i++) {
                float4 a = *(const float4*)&As[(ty << 2) + i][k4];
                acc[i].x = fmaf(a.x, b0.x, acc[i].x);
                acc[i].y = fmaf(a.x, b0.y, acc[i].y);
                acc[i].z = fmaf(a.x, b0.z, acc[i].z);
                acc[i].w = fmaf(a.x, b0.w, acc[i].w);
                acc[i].x = fmaf(a.y, b1.x, acc[i].x);
                acc[i].y = fmaf(a.y, b1.y, acc[i].y);
                acc[i].z = fmaf(a.y, b1.z, acc[i].z);
                acc[i].w = fmaf(a.y, b1.w, acc[i].w);
                acc[i].x = fmaf(a.z, b2.x, acc[i].x);
                acc[i].y = fmaf(a.z, b2.y, acc[i].y);
                acc[i].z = fmaf(a.z, b2.z, acc[i].z);
                acc[i].w = fmaf(a.z, b2.w, acc[i].w);
                acc[i].x = fmaf(a.w, b3.x, acc[i].x);
                acc[i].y = fmaf(a.w, b3.y, acc[i].y);
                acc[i].z = fmaf(a.w, b3.z, acc[i].z);
                acc[i].w = fmaf(a.w, b3.w, acc[i].w);
            }
        }
    }

    float4 bv = *(const float4*)(bias + (tx << 2));
#pragma unroll
    for (int i = 0; i < 4; i++) {
        int node = node0 + (ty << 2) + i;
        if (node < NN) {
            float4 o = make_float4(acc[i].x + bv.x, acc[i].y + bv.y,
                                   acc[i].z + bv.z, acc[i].w + bv.w);
            *(float4*)(out + (size_t)node * F + (tx << 2)) = o;
        }
    }
}

extern "C" void kernel_launch(void* const* d_in, const int* in_sizes, int n_in,
                              void* d_out, int out_size, void* d_ws, size_t ws_size,
                              hipStream_t stream) {
    const float* x    = (const float*)d_in[0];
    const int*   ei   = (const int*)d_in[1];
    const int*   et   = (const int*)d_in[2];
    const float* wgt  = (const float*)d_in[3];
    const float* root = (const float*)d_in[4];
    const float* bias = (const float*)d_in[5];
    float*       out  = (float*)d_out;

    int*      cursors = (int*)d_ws;                                   // [128]
    unsigned* runsd   = (unsigned*)((char*)d_ws + 512);               // [784*16]
    uint2*    stag8   = (uint2*)((char*)d_ws + 512 + 50176);          // 28.9 MB
    unsigned* packed4 = (unsigned*)(stag8 + (size_t)NCB * CAPC);      // 14.5 MB

    init_kernel<<<1, 128, 0, stream>>>(cursors);
    binA_kernel<<<NE / CHUNKA, 256, 0, stream>>>(ei, ei + NE, et, cursors, stag8);
    binB_kernel<<<NCB * 8, 256, 0, stream>>>(stag8, cursors, packed4, runsd);
    fused_kernel<<<NT, 256, 0, stream>>>(x, packed4, runsd, wgt, root, bias, out);
}

// Round 9
// 342.600 us; speedup vs baseline: 4.2514x; 4.2514x over previous
//
#include <hip/hip_runtime.h>

#define NN 100000
#define NE 3200000
#define F 64
#define NR 8
#define PAD 68                 // LDS row stride (floats)
#define NCB 98                 // coarse buckets = ceil(NN/1024), bucket = dst>>10
#define CAPC 36864             // capacity per coarse bucket
#define CHUNKA 4000            // edges per binA block (800 blocks)
#define NT 1563                // node tiles = ceil(NN/64)
#define SLCAP 2560             // per-tile edge list capacity (mean 2048)

// ---------------- init: per-coarse-bucket staging cursors -------------------
__global__ __launch_bounds__(128) void init_kernel(int* __restrict__ cursors) {
    int t = threadIdx.x;
    if (t < NCB) cursors[t] = t * CAPC;
}

// ---------------- pass A: coarse-bin edges (4-copy LDS multi-split) ---------
__global__ __launch_bounds__(256) void binA_kernel(
    const int* __restrict__ esrc, const int* __restrict__ edst,
    const int* __restrict__ etyp,
    int* __restrict__ cursors, uint2* __restrict__ stag8)
{
    __shared__ int hist[128][4];
    __shared__ int start[128];
    __shared__ int cur[128][4];
    __shared__ int gbase[NCB];
    __shared__ uint2 recs[CHUNKA];   // 32 KB

    const int t = threadIdx.x;
    const int cp = t & 3;
    const int e0 = blockIdx.x * CHUNKA;

    if (t < 128) ((int4*)hist)[t] = make_int4(0, 0, 0, 0);
    __syncthreads();

    uint2 rec[16];
#pragma unroll
    for (int j = 0; j < 16; j++) {
        int i = t + j * 256;
        if (i < CHUNKA) {
            int e = e0 + i;
            unsigned s = (unsigned)esrc[e];
            unsigned d = (unsigned)edst[e];
            unsigned r = (unsigned)etyp[e];
            rec[j] = make_uint2(s, d | (r << 17));
            atomicAdd(&hist[d >> 10][cp], 1);
        }
    }
    __syncthreads();

    int tot = 0;
    if (t < 128) {
        int4 h4 = ((int4*)hist)[t];
        tot = h4.x + h4.y + h4.z + h4.w;
        start[t] = tot;
    }
    __syncthreads();
    for (int off = 1; off < 128; off <<= 1) {
        int v = 0;
        if (t < 128 && t >= off) v = start[t - off];
        __syncthreads();
        if (t < 128) start[t] += v;
        __syncthreads();
    }
    if (t < 128) start[t] -= tot;   // inclusive -> exclusive
    __syncthreads();
    if (t < NCB) {
        int4 h4 = ((int4*)hist)[t];
        int s = start[t];
        cur[t][0] = s;
        cur[t][1] = s + h4.x;
        cur[t][2] = s + h4.x + h4.y;
        cur[t][3] = s + h4.x + h4.y + h4.z;
        gbase[t] = atomicAdd(&cursors[t], tot);
    }
    __syncthreads();

#pragma unroll
    for (int j = 0; j < 16; j++) {
        int i = t + j * 256;
        if (i < CHUNKA) {
            int b = (int)((rec[j].y & 0x1FFFFu) >> 10);
            int slot = atomicAdd(&cur[b][cp], 1);
            recs[slot] = rec[j];
        }
    }
    __syncthreads();

#pragma unroll
    for (int j = 0; j < 16; j++) {
        int i = t + j * 256;
        if (i < CHUNKA) {
            uint2 rr = recs[i];
            int b = (int)((rr.y & 0x1FFFFu) >> 10);
            stag8[gbase[b] + (i - start[b])] = rr;
        }
    }
}

// ---------------- pass B: fine-bin, 8 chunk-blocks per coarse bucket --------
__global__ __launch_bounds__(256) void binB_kernel(
    const uint2* __restrict__ stag8, const int* __restrict__ cursors,
    unsigned* __restrict__ packed4, unsigned* __restrict__ runsd)
{
    __shared__ int h[16][4];
    __shared__ int cu[16][4];
    const int b = blockIdx.x >> 3;
    const int c = blockIdx.x & 7;
    const int t = threadIdx.x;
    const int cp = t & 3;
    const int bbase = b * CAPC;
    const int n = cursors[b] - bbase;
    const int s = (int)(((long long)c * n) >> 3);
    const int e = (int)(((long long)(c + 1) * n) >> 3);
    const int base = bbase + s;
    const int cn = e - s;

    if (t < 64) ((int*)h)[t] = 0;
    __syncthreads();
    for (int i = t; i < cn; i += 256) {
        unsigned y = stag8[base + i].y;
        atomicAdd(&h[(y >> 6) & 15][cp], 1);
    }
    __syncthreads();
    if (t == 0) {
        int acc = 0;
        for (int f = 0; f < 16; f++) {
            int fstart = acc;
#pragma unroll
            for (int k = 0; k < 4; k++) { cu[f][k] = acc; acc += h[f][k]; }
            runsd[(blockIdx.x << 4) + f] = ((unsigned)(base + fstart) << 10) | (unsigned)(acc - fstart);
        }
    }
    __syncthreads();
    for (int i = t; i < cn; i += 256) {
        uint2 rr = stag8[base + i];
        unsigned f = (rr.y >> 6) & 15u;
        int p = atomicAdd(&cu[f][cp], 1);
        unsigned d = rr.y & 0x1FFFFu;
        unsigned r = rr.y >> 17;
        packed4[base + p] = rr.x | ((d & 63u) << 17) | (r << 23);
    }
}

// ---------------- fused: LDS sort + reg-gather + GEMM (B direct from L1) ----
// As transposed [k][node] (r5 layout: GEMM a-reads conflict-free, gather
// writes worst 2-way). No Bs: b rows read straight from global (16 KB/seg,
// L1-resident, 4-lane broadcast). LDS total ~31 KB -> 4-5 blocks/CU.
__global__ __launch_bounds__(256) void fused_kernel(
    const float* __restrict__ x,
    const unsigned* __restrict__ packed4,
    const unsigned* __restrict__ runsd,
    const float* __restrict__ weight,   // [8][64][64]
    const float* __restrict__ root,     // [64][64]
    const float* __restrict__ bias,
    float* __restrict__ out)
{
    __shared__ float As[64][PAD];       // As[k][node]
    __shared__ int kstart[512];
    __shared__ int kcur[512];
    __shared__ int slist[SLCAP];
    __shared__ unsigned rdesc[8];

    const int t = threadIdx.x;
    const int tile = blockIdx.x;

    if (t < 8) rdesc[t] = runsd[(((tile >> 4) * 8 + t) << 4) + (tile & 15)];
    kstart[t] = 0; kstart[t + 256] = 0;
    __syncthreads();

    // ---- hist by key9 = rel*64 + dstLow over the 8 runs ----
#pragma unroll
    for (int c = 0; c < 8; c++) {
        unsigned d = rdesc[c];
        int rs = (int)(d >> 10), rc = (int)(d & 1023u);
        for (int i = t; i < rc; i += 256)
            atomicAdd(&kstart[packed4[rs + i] >> 17], 1);
    }
    __syncthreads();
    int a0 = kstart[2 * t], a1 = kstart[2 * t + 1];
    int psum = a0 + a1;
    kcur[t] = psum;
    __syncthreads();
    for (int off = 1; off < 256; off <<= 1) {
        int v = (t >= off) ? kcur[t - off] : 0;
        __syncthreads();
        kcur[t] += v;
        __syncthreads();
    }
    int ebase = kcur[t] - psum;
    __syncthreads();
    kstart[2 * t]     = ebase;
    kstart[2 * t + 1] = ebase + a0;
    kcur[2 * t]       = ebase;
    kcur[2 * t + 1]   = ebase + a0;
    __syncthreads();
#pragma unroll
    for (int c = 0; c < 8; c++) {
        unsigned d = rdesc[c];
        int rs = (int)(d >> 10), rc = (int)(d & 1023u);
        for (int i = t; i < rc; i += 256) {
            unsigned p = packed4[rs + i];
            int slot = atomicAdd(&kcur[p >> 17], 1);
            slist[slot] = (int)(p & 0x1FFFFu);   // src only; runs are per-key
        }
    }
    __syncthreads();   // kcur[k] == end of run k

    const int tx = t & 15;    // fout group
    const int ty = t >> 4;    // node group
    const int node0 = tile * 64;
    const int sn = t >> 2;    // staging node 0..63
    const int sq = t & 3;     // staging quarter 0..3
    const int nclamp = min(node0 + sn, NN - 1);

    float acc[4][4];
#pragma unroll
    for (int i = 0; i < 4; i++)
#pragma unroll
        for (int j = 0; j < 4; j++) acc[i][j] = 0.f;

    for (int seg = 0; seg < 9; seg++) {
        const float* __restrict__ Wseg = (seg == 0) ? root : (weight + (size_t)(seg - 1) * (F * F));
        __syncthreads();   // As free (prev GEMM done)

        // stage A (transposed, scaled); thread owns k-chunks {4sq+16j}, j=0..3
        const int k0 = sq << 2;
        if (seg == 0) {
            const float* rowp = x + (size_t)nclamp * F;
#pragma unroll
            for (int j = 0; j < 4; j++) {
                int kc = k0 + 16 * j;
                float4 v = *(const float4*)(rowp + kc);
                As[kc + 0][sn] = v.x;
                As[kc + 1][sn] = v.y;
                As[kc + 2][sn] = v.z;
                As[kc + 3][sn] = v.w;
            }
        } else {
            const int key = ((seg - 1) << 6) | sn;
            const int beg = kstart[key];
            const int end = kcur[key];
            float4 a0v = make_float4(0.f, 0.f, 0.f, 0.f);
            float4 a1v = a0v, a2v = a0v, a3v = a0v;
            for (int i = beg; i < end; i++) {
                const float* xr = x + (size_t)slist[i] * F + k0;
                float4 v0 = *(const float4*)(xr);
                float4 v1 = *(const float4*)(xr + 16);
                float4 v2 = *(const float4*)(xr + 32);
                float4 v3 = *(const float4*)(xr + 48);
                a0v.x += v0.x; a0v.y += v0.y; a0v.z += v0.z; a0v.w += v0.w;
                a1v.x += v1.x; a1v.y += v1.y; a1v.z += v1.z; a1v.w += v1.w;
                a2v.x += v2.x; a2v.y += v2.y; a2v.z += v2.z; a2v.w += v2.w;
                a3v.x += v3.x; a3v.y += v3.y; a3v.z += v3.z; a3v.w += v3.w;
            }
            float scl = 1.0f / (float)max(end - beg, 1);
            As[k0 +  0][sn] = a0v.x * scl; As[k0 +  1][sn] = a0v.y * scl;
            As[k0 +  2][sn] = a0v.z * scl; As[k0 +  3][sn] = a0v.w * scl;
            As[k0 + 16][sn] = a1v.x * scl; As[k0 + 17][sn] = a1v.y * scl;
            As[k0 + 18][sn] = a1v.z * scl; As[k0 + 19][sn] = a1v.w * scl;
            As[k0 + 32][sn] = a2v.x * scl; As[k0 + 33][sn] = a2v.y * scl;
            As[k0 + 34][sn] = a2v.z * scl; As[k0 + 35][sn] = a2v.w * scl;
            As[k0 + 48][sn] = a3v.x * scl; As[k0 + 49][sn] = a3v.y * scl;
            As[k0 + 50][sn] = a3v.z * scl; As[k0 + 51][sn] = a3v.w * scl;
        }
        __syncthreads();

        // GEMM: a from LDS (conflict-free), b from global (L1-hot 16 KB)
#pragma unroll 8
        for (int k = 0; k < 64; k++) {
            float4 a = *(const float4*)&As[k][ty << 2];
            float4 b = *(const float4*)(Wseg + (k << 6) + (tx << 2));
            acc[0][0] = fmaf(a.x, b.x, acc[0][0]);
            acc[0][1] = fmaf(a.x, b.y, acc[0][1]);
            acc[0][2] = fmaf(a.x, b.z, acc[0][2]);
            acc[0][3] = fmaf(a.x, b.w, acc[0][3]);
            acc[1][0] = fmaf(a.y, b.x, acc[1][0]);
            acc[1][1] = fmaf(a.y, b.y, acc[1][1]);
            acc[1][2] = fmaf(a.y, b.z, acc[1][2]);
            acc[1][3] = fmaf(a.y, b.w, acc[1][3]);
            acc[2][0] = fmaf(a.z, b.x, acc[2][0]);
            acc[2][1] = fmaf(a.z, b.y, acc[2][1]);
            acc[2][2] = fmaf(a.z, b.z, acc[2][2]);
            acc[2][3] = fmaf(a.z, b.w, acc[2][3]);
            acc[3][0] = fmaf(a.w, b.x, acc[3][0]);
            acc[3][1] = fmaf(a.w, b.y, acc[3][1]);
            acc[3][2] = fmaf(a.w, b.z, acc[3][2]);
            acc[3][3] = fmaf(a.w, b.w, acc[3][3]);
        }
    }

    // epilogue: + bias, coalesced float4 stores
    float4 bv = *(const float4*)(bias + (tx << 2));
#pragma unroll
    for (int i = 0; i < 4; i++) {
        int node = node0 + (ty << 2) + i;
        if (node < NN) {
            float4 o = make_float4(acc[i][0] + bv.x, acc[i][1] + bv.y,
                                   acc[i][2] + bv.z, acc[i][3] + bv.w);
            *(float4*)(out + (size_t)node * F + (tx << 2)) = o;
        }
    }
}

extern "C" void kernel_launch(void* const* d_in, const int* in_sizes, int n_in,
                              void* d_out, int out_size, void* d_ws, size_t ws_size,
                              hipStream_t stream) {
    const float* x    = (const float*)d_in[0];
    const int*   ei   = (const int*)d_in[1];
    const int*   et   = (const int*)d_in[2];
    const float* wgt  = (const float*)d_in[3];
    const float* root = (const float*)d_in[4];
    const float* bias = (const float*)d_in[5];
    float*       out  = (float*)d_out;

    int*      cursors = (int*)d_ws;                                   // [128]
    unsigned* runsd   = (unsigned*)((char*)d_ws + 512);               // [784*16]
    uint2*    stag8   = (uint2*)((char*)d_ws + 512 + 50176);          // 28.9 MB
    unsigned* packed4 = (unsigned*)(stag8 + (size_t)NCB * CAPC);      // 14.5 MB

    init_kernel<<<1, 128, 0, stream>>>(cursors);
    binA_kernel<<<NE / CHUNKA, 256, 0, stream>>>(ei, ei + NE, et, cursors, stag8);
    binB_kernel<<<NCB * 8, 256, 0, stream>>>(stag8, cursors, packed4, runsd);
    fused_kernel<<<NT, 256, 0, stream>>>(x, packed4, runsd, wgt, root, bias, out);
}